// Round 13
// baseline (30.515 us; speedup 1.0000x reference)
//
#include <hip/hip_runtime.h>

#define SLEN   300
#define PT     20
#define STEP   4
#define MAXD   2
#define NBANDS 2
#define NS     30
#define NGAL   8
#define BATCH  8
#define N1     71            // (300-20)/4+1
#define NPT    (N1*N1)       // 5041
#define NSUB   (BATCH*NPT)   // 40328

// ---- output layout (flat float32, in reference return order) ----
#define OFF_LOCS 32262400
#define OFF_GAL  32423712
#define OFF_FLUX 33068960
#define OFF_N    33230272
#define OFF_ISON 33270600

// R9 emit loop, coarser blocks: one FULL i-row per tile block (71 patches,
// tot = 14200 compile-time constant). 568 tile + 158 catalog = 726 blocks
// (~2.8 blocks/CU, single round) -> half the launch ramp / per-block
// prologue overhead of R9's 1294 blocks. XCD swizzle: 568 = 8*71, XCD k
// gets exactly batch k (720 KB L2-resident image footprint).
#define TILE_BLOCKS (BATCH * N1)              // 568 = 8 * 71
#define CAT_BLOCKS  ((NSUB + 255) / 256)      // 158
#define CHUNK (TILE_BLOCKS / 8)               // 71 blocks per XCD (= 1 batch)

typedef float vf4 __attribute__((ext_vector_type(4)));

__global__ __launch_bounds__(256) void fused_kernel(
    const float* __restrict__ img,
    const float* __restrict__ locs,
    const float* __restrict__ gal,
    const float* __restrict__ flux,
    float* __restrict__ out)
{
    const int bid = blockIdx.x;
    const int tid = threadIdx.x;

    if (bid < TILE_BLOCKS) {
        // ---------------- patch extraction (direct L1/L2-cached reads) -----
        const int wg = (bid & 7) * CHUNK + (bid >> 3);   // bijective XCD swizzle
        const int i  = wg % N1;
        const int b  = wg / N1;

        const int sub0 = b * NPT + i * N1;
        vf4* dst = reinterpret_cast<vf4*>(out) + (size_t)sub0 * 200;
        const float* imb = img + (size_t)b * NBANDS * SLEN * SLEN
                               + (size_t)(i * STEP) * SLEN;
        const int tot = N1 * 200;   // 14200, compile-time constant
        // w == jj*200 + c*100 + rr*5 + q
        for (int w = tid; w < tot; w += 256) {
            int jj  = w / 200;
            int rem = w - jj * 200;
            int c   = rem / 100;
            int r2  = rem - c * 100;
            int rr  = r2 / 5;
            int q   = r2 - rr * 5;
            const vf4 v = *reinterpret_cast<const vf4*>(
                imb + ((size_t)(c * SLEN + rr)) * SLEN + jj * 4 + q * 4);
            dst[w] = v;
        }
    } else {
        // ---------------- per-tile catalog ----------------
        const int sub = (bid - TILE_BLOCKS) * 256 + tid;
        if (sub >= NSUB) return;

        const int b = sub / NPT;
        const int t = sub % NPT;
        const int i = t / N1;
        const int j = t % N1;

        const float lox = (float)(i * STEP) + 1.5f;   // tc.x + EP - 0.5
        const float loy = (float)(j * STEP) + 1.5f;
        const float hix = lox + 16.0f;                // tc - 0.5 + PT - EP
        const float hiy = loy + 16.0f;

        int   cnt = 0;
        int   sid[2] = {0, 0};
        float slx[2] = {0.f, 0.f};
        float sly[2] = {0.f, 0.f};

        const float* lb = locs + (size_t)b * NS * 2;
        #pragma unroll
        for (int s = 0; s < NS; ++s) {
            float lx = lb[2 * s + 0] * (float)(SLEN - 1);
            float ly = lb[2 * s + 1] * (float)(SLEN - 1);
            bool on = (lx > lox) && (lx < hix) && (ly > loy) && (ly < hiy);
            if (on) {
                if (cnt < MAXD) { sid[cnt] = s; slx[cnt] = lx; sly[cnt] = ly; }
                cnt++;
            }
        }

        const float inv_scale = 1.0f / 16.0f;  // 1/(PT-2*EP), exact

        float4 lv;
        lv.x = (cnt > 0) ? fmaxf((slx[0] - lox) * inv_scale, 0.0f) : 0.0f;
        lv.y = (cnt > 0) ? fmaxf((sly[0] - loy) * inv_scale, 0.0f) : 0.0f;
        lv.z = (cnt > 1) ? fmaxf((slx[1] - lox) * inv_scale, 0.0f) : 0.0f;
        lv.w = (cnt > 1) ? fmaxf((sly[1] - loy) * inv_scale, 0.0f) : 0.0f;
        reinterpret_cast<float4*>(out + OFF_LOCS)[sub] = lv;

        float4 g0 = {0,0,0,0}, g1 = {0,0,0,0}, g2 = {0,0,0,0}, g3 = {0,0,0,0};
        if (cnt > 0) {
            const float4* gp = reinterpret_cast<const float4*>(
                gal + ((size_t)(b * NS + sid[0])) * NGAL);
            g0 = gp[0]; g1 = gp[1];
        }
        if (cnt > 1) {
            const float4* gp = reinterpret_cast<const float4*>(
                gal + ((size_t)(b * NS + sid[1])) * NGAL);
            g2 = gp[0]; g3 = gp[1];
        }
        float4* go = reinterpret_cast<float4*>(out + OFF_GAL) + (size_t)sub * 4;
        go[0] = g0; go[1] = g1; go[2] = g2; go[3] = g3;

        float4 fv = {0,0,0,0};
        if (cnt > 0) {
            const float2 f = reinterpret_cast<const float2*>(
                flux + ((size_t)(b * NS + sid[0])) * NBANDS)[0];
            fv.x = f.x; fv.y = f.y;
        }
        if (cnt > 1) {
            const float2 f = reinterpret_cast<const float2*>(
                flux + ((size_t)(b * NS + sid[1])) * NBANDS)[0];
            fv.z = f.x; fv.w = f.y;
        }
        reinterpret_cast<float4*>(out + OFF_FLUX)[sub] = fv;

        out[OFF_N + sub] = (float)(cnt < MAXD ? cnt : MAXD);
        float2 ison;
        ison.x = (cnt > 0) ? 1.0f : 0.0f;
        ison.y = (cnt > 1) ? 1.0f : 0.0f;
        reinterpret_cast<float2*>(out + OFF_ISON)[sub] = ison;
    }
}

extern "C" void kernel_launch(void* const* d_in, const int* in_sizes, int n_in,
                              void* d_out, int out_size, void* d_ws, size_t ws_size,
                              hipStream_t stream)
{
    const float* images = (const float*)d_in[0];
    const float* locs   = (const float*)d_in[1];
    const float* gal    = (const float*)d_in[2];
    const float* flux   = (const float*)d_in[3];
    float* out = (float*)d_out;

    fused_kernel<<<TILE_BLOCKS + CAT_BLOCKS, 256, 0, stream>>>(
        images, locs, gal, flux, out);
}

// Round 14
// 28.759 us; speedup vs baseline: 1.0610x; 1.0610x over previous
//
#include <hip/hip_runtime.h>

#define SLEN   300
#define PT     20
#define STEP   4
#define MAXD   2
#define NBANDS 2
#define NS     30
#define NGAL   8
#define BATCH  8
#define N1     71            // (300-20)/4+1
#define NPT    (N1*N1)       // 5041
#define NSUB   (BATCH*NPT)   // 40328

// ---- output layout (flat float32, in reference return order) ----
#define OFF_LOCS 32262400
#define OFF_GAL  32423712
#define OFF_FLUX 33068960
#define OFF_N    33230272
#define OFF_ISON 33270600

// Block-count series on the SAME emit loop: 726 blocks -> 30.5us,
// 1294 -> 27.1us (block-granularity: critical-CU work = ceil(heavy/256) x
// per-block work). Thirds decomposition: 1704 tile blocks (24/24/23
// patches) + 158 catalog = 1862 < 2048 -> still single-round, worst-CU
// quantum 7 x 4800 f4 = 33.6K f4 vs R9's 5 x 7200 = 36K.
// XCD swizzle exact: 1704 = 8*213, XCD k == batch k (720 KB L2 footprint).
#define THIRDS 3
#define TILE_BLOCKS (BATCH * N1 * THIRDS)     // 1704 = 8 * 213
#define CAT_BLOCKS  ((NSUB + 255) / 256)      // 158
#define CHUNK (TILE_BLOCKS / 8)               // 213 blocks per XCD (= 1 batch)

typedef float vf4 __attribute__((ext_vector_type(4)));

__global__ __launch_bounds__(256) void fused_kernel(
    const float* __restrict__ img,
    const float* __restrict__ locs,
    const float* __restrict__ gal,
    const float* __restrict__ flux,
    float* __restrict__ out)
{
    const int bid = blockIdx.x;
    const int tid = threadIdx.x;

    if (bid < TILE_BLOCKS) {
        // ---------------- patch extraction (direct L1/L2-cached reads) -----
        const int wg = (bid & 7) * CHUNK + (bid >> 3);   // bijective XCD swizzle
        const int t3 = wg % THIRDS;          // third of the i-row
        const int bi = wg / THIRDS;
        const int i  = bi % N1;
        const int b  = bi / N1;
        const int j0 = t3 * 24;
        const int nj = (t3 == 2) ? 23 : 24;
        const int col0 = j0 * STEP;
        const int i4   = i * STEP;

        const int sub0 = b * NPT + i * N1 + j0;
        vf4* dst = reinterpret_cast<vf4*>(out) + (size_t)sub0 * 200;
        const float* imb = img + (size_t)b * NBANDS * SLEN * SLEN
                               + (size_t)i4 * SLEN + col0;
        const int tot = nj * 200;   // within-chunk w == jj*200 + c*100 + rr*5 + q

        for (int w = tid; w < tot; w += 256) {
            int jj  = w / 200;
            int rem = w - jj * 200;
            int c   = rem / 100;
            int r2  = rem - c * 100;
            int rr  = r2 / 5;
            int q   = r2 - rr * 5;
            const vf4 v = *reinterpret_cast<const vf4*>(
                imb + ((size_t)(c * SLEN + rr)) * SLEN + jj * 4 + q * 4);
            dst[w] = v;
        }
    } else {
        // ---------------- per-tile catalog ----------------
        const int sub = (bid - TILE_BLOCKS) * 256 + tid;
        if (sub >= NSUB) return;

        const int b = sub / NPT;
        const int t = sub % NPT;
        const int i = t / N1;
        const int j = t % N1;

        const float lox = (float)(i * STEP) + 1.5f;   // tc.x + EP - 0.5
        const float loy = (float)(j * STEP) + 1.5f;
        const float hix = lox + 16.0f;                // tc - 0.5 + PT - EP
        const float hiy = loy + 16.0f;

        int   cnt = 0;
        int   sid[2] = {0, 0};
        float slx[2] = {0.f, 0.f};
        float sly[2] = {0.f, 0.f};

        const float* lb = locs + (size_t)b * NS * 2;
        #pragma unroll
        for (int s = 0; s < NS; ++s) {
            float lx = lb[2 * s + 0] * (float)(SLEN - 1);
            float ly = lb[2 * s + 1] * (float)(SLEN - 1);
            bool on = (lx > lox) && (lx < hix) && (ly > loy) && (ly < hiy);
            if (on) {
                if (cnt < MAXD) { sid[cnt] = s; slx[cnt] = lx; sly[cnt] = ly; }
                cnt++;
            }
        }

        const float inv_scale = 1.0f / 16.0f;  // 1/(PT-2*EP), exact

        float4 lv;
        lv.x = (cnt > 0) ? fmaxf((slx[0] - lox) * inv_scale, 0.0f) : 0.0f;
        lv.y = (cnt > 0) ? fmaxf((sly[0] - loy) * inv_scale, 0.0f) : 0.0f;
        lv.z = (cnt > 1) ? fmaxf((slx[1] - lox) * inv_scale, 0.0f) : 0.0f;
        lv.w = (cnt > 1) ? fmaxf((sly[1] - loy) * inv_scale, 0.0f) : 0.0f;
        reinterpret_cast<float4*>(out + OFF_LOCS)[sub] = lv;

        float4 g0 = {0,0,0,0}, g1 = {0,0,0,0}, g2 = {0,0,0,0}, g3 = {0,0,0,0};
        if (cnt > 0) {
            const float4* gp = reinterpret_cast<const float4*>(
                gal + ((size_t)(b * NS + sid[0])) * NGAL);
            g0 = gp[0]; g1 = gp[1];
        }
        if (cnt > 1) {
            const float4* gp = reinterpret_cast<const float4*>(
                gal + ((size_t)(b * NS + sid[1])) * NGAL);
            g2 = gp[0]; g3 = gp[1];
        }
        float4* go = reinterpret_cast<float4*>(out + OFF_GAL) + (size_t)sub * 4;
        go[0] = g0; go[1] = g1; go[2] = g2; go[3] = g3;

        float4 fv = {0,0,0,0};
        if (cnt > 0) {
            const float2 f = reinterpret_cast<const float2*>(
                flux + ((size_t)(b * NS + sid[0])) * NBANDS)[0];
            fv.x = f.x; fv.y = f.y;
        }
        if (cnt > 1) {
            const float2 f = reinterpret_cast<const float2*>(
                flux + ((size_t)(b * NS + sid[1])) * NBANDS)[0];
            fv.z = f.x; fv.w = f.y;
        }
        reinterpret_cast<float4*>(out + OFF_FLUX)[sub] = fv;

        out[OFF_N + sub] = (float)(cnt < MAXD ? cnt : MAXD);
        float2 ison;
        ison.x = (cnt > 0) ? 1.0f : 0.0f;
        ison.y = (cnt > 1) ? 1.0f : 0.0f;
        reinterpret_cast<float2*>(out + OFF_ISON)[sub] = ison;
    }
}

extern "C" void kernel_launch(void* const* d_in, const int* in_sizes, int n_in,
                              void* d_out, int out_size, void* d_ws, size_t ws_size,
                              hipStream_t stream)
{
    const float* images = (const float*)d_in[0];
    const float* locs   = (const float*)d_in[1];
    const float* gal    = (const float*)d_in[2];
    const float* flux   = (const float*)d_in[3];
    float* out = (float*)d_out;

    fused_kernel<<<TILE_BLOCKS + CAT_BLOCKS, 256, 0, stream>>>(
        images, locs, gal, flux, out);
}

// Round 15
// 28.178 us; speedup vs baseline: 1.0829x; 1.0206x over previous
//
#include <hip/hip_runtime.h>

#define SLEN   300
#define PT     20
#define STEP   4
#define MAXD   2
#define NBANDS 2
#define NS     30
#define NGAL   8
#define BATCH  8
#define N1     71            // (300-20)/4+1
#define NPT    (N1*N1)       // 5041
#define NSUB   (BATCH*NPT)   // 40328

// ---- output layout (flat float32, in reference return order) ----
#define OFF_LOCS 32262400
#define OFF_GAL  32423712
#define OFF_FLUX 33068960
#define OFF_N    33230272
#define OFF_ISON 33270600

// Memset-shaped store stream, XCD-partitioned: XCD k's 236 blocks x 256
// threads grid-stride (stride 60416 f4) over batch k's 1,008,200 output
// f4s -> the chip's stores form 8 contiguous ~1MB windows marching
// linearly (the shape that sustains 7.1 TB/s in the fill memset), while
// reads stay on batch k's 720 KB L2-resident image. 1888 + 158 = 2046
// blocks <= 2048 capacity (single round).
#define TPX   236                            // tile blocks per XCD
#define TILE_BLOCKS (8 * TPX)                // 1888
#define CAT_BLOCKS  ((NSUB + 255) / 256)     // 158
#define PB    (NPT * 200)                    // 1,008,200 f4 per batch
#define XTHREADS (TPX * 256)                 // 60,416

typedef float vf4 __attribute__((ext_vector_type(4)));

__global__ __launch_bounds__(256) void fused_kernel(
    const float* __restrict__ img,
    const float* __restrict__ locs,
    const float* __restrict__ gal,
    const float* __restrict__ flux,
    float* __restrict__ out)
{
    const int bid = blockIdx.x;
    const int tid = threadIdx.x;

    if (bid < TILE_BLOCKS) {
        // ---------------- patch extraction, flat grid-stride per XCD -------
        const int xcd = bid & 7;             // HW round-robins bid across XCDs
        const int b   = xcd;                 // batch = XCD
        const int gt  = (bid >> 3) * 256 + tid;   // 0..60415 within XCD group
        const float* imb = img + (size_t)b * NBANDS * SLEN * SLEN;
        vf4* dstb = reinterpret_cast<vf4*>(out) + (size_t)b * PB;

        // w == (i*71+j)*200 + c*100 + rr*5 + q
        for (int w = gt; w < PB; w += XTHREADS) {
            int sub = w / 200;               // patch within batch
            int rem = w - sub * 200;
            int i   = sub / N1;
            int j   = sub - i * N1;
            int c   = rem / 100;
            int r2  = rem - c * 100;
            int rr  = r2 / 5;
            int q   = r2 - rr * 5;
            const vf4 v = *reinterpret_cast<const vf4*>(
                imb + (size_t)(c * SLEN + i * STEP + rr) * SLEN
                    + j * STEP + q * 4);
            dstb[w] = v;
        }
    } else {
        // ---------------- per-tile catalog ----------------
        const int sub = (bid - TILE_BLOCKS) * 256 + tid;
        if (sub >= NSUB) return;

        const int b = sub / NPT;
        const int t = sub % NPT;
        const int i = t / N1;
        const int j = t % N1;

        const float lox = (float)(i * STEP) + 1.5f;   // tc.x + EP - 0.5
        const float loy = (float)(j * STEP) + 1.5f;
        const float hix = lox + 16.0f;                // tc - 0.5 + PT - EP
        const float hiy = loy + 16.0f;

        int   cnt = 0;
        int   sid[2] = {0, 0};
        float slx[2] = {0.f, 0.f};
        float sly[2] = {0.f, 0.f};

        const float* lb = locs + (size_t)b * NS * 2;
        #pragma unroll
        for (int s = 0; s < NS; ++s) {
            float lx = lb[2 * s + 0] * (float)(SLEN - 1);
            float ly = lb[2 * s + 1] * (float)(SLEN - 1);
            bool on = (lx > lox) && (lx < hix) && (ly > loy) && (ly < hiy);
            if (on) {
                if (cnt < MAXD) { sid[cnt] = s; slx[cnt] = lx; sly[cnt] = ly; }
                cnt++;
            }
        }

        const float inv_scale = 1.0f / 16.0f;  // 1/(PT-2*EP), exact

        float4 lv;
        lv.x = (cnt > 0) ? fmaxf((slx[0] - lox) * inv_scale, 0.0f) : 0.0f;
        lv.y = (cnt > 0) ? fmaxf((sly[0] - loy) * inv_scale, 0.0f) : 0.0f;
        lv.z = (cnt > 1) ? fmaxf((slx[1] - lox) * inv_scale, 0.0f) : 0.0f;
        lv.w = (cnt > 1) ? fmaxf((sly[1] - loy) * inv_scale, 0.0f) : 0.0f;
        reinterpret_cast<float4*>(out + OFF_LOCS)[sub] = lv;

        float4 g0 = {0,0,0,0}, g1 = {0,0,0,0}, g2 = {0,0,0,0}, g3 = {0,0,0,0};
        if (cnt > 0) {
            const float4* gp = reinterpret_cast<const float4*>(
                gal + ((size_t)(b * NS + sid[0])) * NGAL);
            g0 = gp[0]; g1 = gp[1];
        }
        if (cnt > 1) {
            const float4* gp = reinterpret_cast<const float4*>(
                gal + ((size_t)(b * NS + sid[1])) * NGAL);
            g2 = gp[0]; g3 = gp[1];
        }
        float4* go = reinterpret_cast<float4*>(out + OFF_GAL) + (size_t)sub * 4;
        go[0] = g0; go[1] = g1; go[2] = g2; go[3] = g3;

        float4 fv = {0,0,0,0};
        if (cnt > 0) {
            const float2 f = reinterpret_cast<const float2*>(
                flux + ((size_t)(b * NS + sid[0])) * NBANDS)[0];
            fv.x = f.x; fv.y = f.y;
        }
        if (cnt > 1) {
            const float2 f = reinterpret_cast<const float2*>(
                flux + ((size_t)(b * NS + sid[1])) * NBANDS)[0];
            fv.z = f.x; fv.w = f.y;
        }
        reinterpret_cast<float4*>(out + OFF_FLUX)[sub] = fv;

        out[OFF_N + sub] = (float)(cnt < MAXD ? cnt : MAXD);
        float2 ison;
        ison.x = (cnt > 0) ? 1.0f : 0.0f;
        ison.y = (cnt > 1) ? 1.0f : 0.0f;
        reinterpret_cast<float2*>(out + OFF_ISON)[sub] = ison;
    }
}

extern "C" void kernel_launch(void* const* d_in, const int* in_sizes, int n_in,
                              void* d_out, int out_size, void* d_ws, size_t ws_size,
                              hipStream_t stream)
{
    const float* images = (const float*)d_in[0];
    const float* locs   = (const float*)d_in[1];
    const float* gal    = (const float*)d_in[2];
    const float* flux   = (const float*)d_in[3];
    float* out = (float*)d_out;

    fused_kernel<<<TILE_BLOCKS + CAT_BLOCKS, 256, 0, stream>>>(
        images, locs, gal, flux, out);
}